// Round 10
// baseline (133.474 us; speedup 1.0000x reference)
//
#include <hip/hip_runtime.h>
#include <math.h>

#define EPS 1e-9f

constexpr int Bn = 1024, Dn = 512, Un = 512;
constexpr int BM = 32;      // rows of B per block (2048 blocks = 8/CU)
constexpr int BU = 64;      // cols of U per block
constexpr int DK = 16;      // k-chunk staged in LDS (14KB/block)
constexpr int SPLITD = 8;   // D split across blocks; 16MB ws (proven path)
constexpr int DPB = Dn / SPLITD;    // 64 d per block
constexpr int NCHUNK = DPB / DK;    // 4 chunks

typedef float v4f __attribute__((ext_vector_type(4)));
typedef int   v4i __attribute__((ext_vector_type(4)));

// XOR swizzle for sL columns (R6-proven: conflicts -> 0).
__device__ __forceinline__ int swz(int d) { return ((d >> 2) & 3) << 3; }

// Packed main-pipe exp2: clamp + magic-round + deg-3 poly + bit-built scale.
// Replaces quarter-rate v_exp_f32 (16 cyc/wave-instr) with ~10 cyc of
// full-rate (mostly v_pk_*) work per 4 elements. Rel err ~8e-4 (threshold
// slack is ~1e12x). Clamp at -126 matches v_exp's flush-to-zero for the
// tiny-|x|, large-p corner; in-data t <= ~75 needs no high clamp.
__device__ __forceinline__ v4f fast_exp2(v4f t) {
    const float MAGIC = 12582912.0f;           // 1.5 * 2^23
    v4f tc = __builtin_elementwise_max(t, (v4f)(-126.0f));
    const v4f m = tc + MAGIC;                  // low mantissa bits = round(t)
    const v4f r = m - MAGIC;                   // round(t) as float
    const v4f f = tc - r;                      // f in [-0.5, 0.5]
    v4f q = (v4f)(0.0554803f);
    q = __builtin_elementwise_fma(q, f, (v4f)(0.2402265f));
    q = __builtin_elementwise_fma(q, f, (v4f)(0.6931472f));
    q = __builtin_elementwise_fma(q, f, (v4f)(1.0f));
    v4i mi;
    __builtin_memcpy(&mi, &m, 16);
    const v4i si = (mi + (127 - 0x400000)) << 23;   // as_int(2^round(t))
    v4f s;
    __builtin_memcpy(&s, &si, 16);
    return q * s;
}

template <bool USE_WS>
__global__ __launch_bounds__(256, 4) void power_layer(
    const float* __restrict__ x, const float* __restrict__ w,
    const float* __restrict__ p, const float* __restrict__ bias,
    float* __restrict__ outp)
{
    __shared__ float sL[DK][BM];   // Lenc = sign(neg)*(log2|x+eps|+64), swizzled cols
    __shared__ float sP[DK][BU];   // p
    __shared__ float sW[DK][BU];   // w
    __shared__ float sWX[DK][BU];  // odd(p) ? -w : w

    const int tid = threadIdx.x;
    const int tx  = tid & 15;
    const int ty  = tid >> 4;
    const int tx4 = tx * 4;
    const int ty2 = ty * 2;
    const int ub = blockIdx.x * BU;
    const int bb = blockIdx.y * BM;
    const int d0 = blockIdx.z * DPB;

    v4f acc[2] = {};   // 2 rows x 4 cols per thread

    for (int ch = 0; ch < NCHUNK; ++ch) {
        const int db = d0 + ch * DK;

        // ---- stage x tile -> sL (32 rows x 16 d, transposed+swizzled) ----
        if (tid < 128) {
            const int r  = tid >> 2;          // 0..31
            const int dq = (tid & 3) << 2;    // 0,4,8,12
            const float4 xv = *reinterpret_cast<const float4*>(
                &x[(size_t)(bb + r) * Dn + db + dq]);
            const float* xs = reinterpret_cast<const float*>(&xv);
            #pragma unroll
            for (int j = 0; j < 4; ++j) {
                const float xe = xs[j] + EPS;
                const float La = __builtin_amdgcn_logf(fabsf(xe)) + 64.0f;
                const int dd = dq + j;
                sL[dd][r ^ swz(dd)] = (xe < 0.0f) ? -La : La;
            }
        }
        // ---- stage p,w tiles (16 d x 64 u, natural layout, 1 float4/thread) ----
        {
            const int d  = tid >> 4;          // 0..15
            const int uq = (tid & 15) << 2;   // 0..60
            const size_t gi = (size_t)(db + d) * Un + ub + uq;
            const float4 pv = *reinterpret_cast<const float4*>(&p[gi]);
            const float4 wv = *reinterpret_cast<const float4*>(&w[gi]);
            const float* ps  = reinterpret_cast<const float*>(&pv);
            const float* wsv = reinterpret_cast<const float*>(&wv);
            float4 wxv;
            float* wxs = reinterpret_cast<float*>(&wxv);
            #pragma unroll
            for (int j = 0; j < 4; ++j) {
                const bool odd = (fmodf(ps[j], 2.0f) != 0.0f);
                wxs[j] = odd ? -wsv[j] : wsv[j];
            }
            *reinterpret_cast<float4*>(&sP[d][uq])  = pv;
            *reinterpret_cast<float4*>(&sW[d][uq])  = wv;
            *reinterpret_cast<float4*>(&sWX[d][uq]) = wxv;
        }
        __syncthreads();

        // ---- inner loop: per d, per-row ADDRESS-selected weight fragment ----
        #pragma unroll 4
        for (int d = 0; d < DK; ++d) {
            const float2 Lv = *reinterpret_cast<const float2*>(&sL[d][ty2 ^ swz(d)]);
            const v4f    Pv = *reinterpret_cast<const v4f*>(&sP[d][tx4]);
            const float* Ls = reinterpret_cast<const float*>(&Lv);

            #pragma unroll
            for (int r = 0; r < 2; ++r) {
                const float Ld = fabsf(Ls[r]) - 64.0f;
                const bool  ng = Ls[r] < 0.0f;
                const v4f Wsel = *reinterpret_cast<const v4f*>(
                    ng ? &sWX[d][tx4] : &sW[d][tx4]);

                const v4f e = fast_exp2(Pv * Ld);
                acc[r] = __builtin_elementwise_fma(Wsel, e, acc[r]);
            }
        }
        __syncthreads();
    }

    if (USE_WS) {
        // plain coalesced partial stores: ws[z][b][u]
        float* dst = outp + ((size_t)blockIdx.z * Bn + bb + ty2) * Un + ub + tx4;
        #pragma unroll
        for (int r = 0; r < 2; ++r)
            *reinterpret_cast<v4f*>(dst + (size_t)r * Un) = acc[r];
    } else {
        if (blockIdx.z == 0) {
            const v4f bv = *reinterpret_cast<const v4f*>(&bias[ub + tx4]);
            #pragma unroll
            for (int r = 0; r < 2; ++r)
                acc[r] += bv;
        }
        #pragma unroll
        for (int r = 0; r < 2; ++r) {
            const int row = bb + ty2 + r;
            #pragma unroll
            for (int c = 0; c < 4; ++c)
                atomicAdd(&outp[(size_t)row * Un + ub + tx4 + c], acc[r][c]);
        }
    }
}

// out[b,u] = sum_z ws[z][b][u] + bias[u]   (float4 per thread)
__global__ __launch_bounds__(256) void reduce_ws(
    const float* __restrict__ ws, const float* __restrict__ bias,
    float* __restrict__ out)
{
    const int nf4 = (Bn * Un) / 4;   // 131072
    const int i = blockIdx.x * 256 + threadIdx.x;
    if (i >= nf4) return;
    const v4f* w4 = reinterpret_cast<const v4f*>(ws);
    v4f a = w4[i];
    #pragma unroll
    for (int z = 1; z < SPLITD; ++z)
        a += w4[(size_t)z * nf4 + i];
    a += reinterpret_cast<const v4f*>(bias)[i & (Un / 4 - 1)];
    reinterpret_cast<v4f*>(out)[i] = a;
}

extern "C" void kernel_launch(void* const* d_in, const int* in_sizes, int n_in,
                              void* d_out, int out_size, void* d_ws, size_t ws_size,
                              hipStream_t stream) {
    const float* x = (const float*)d_in[0];
    const float* w = (const float*)d_in[1];
    const float* p = (const float*)d_in[2];
    const float* b = (const float*)d_in[3];
    float* out = (float*)d_out;

    const dim3 grid(Un / BU, Bn / BM, SPLITD);   // 8 x 32 x 8 = 2048 blocks
    const size_t need = (size_t)SPLITD * Bn * Un * sizeof(float);   // 16 MB

    if (ws_size >= need) {
        float* wsf = (float*)d_ws;
        power_layer<true><<<grid, dim3(256), 0, stream>>>(x, w, p, b, wsf);
        reduce_ws<<<dim3((Bn * Un / 4 + 255) / 256), dim3(256), 0, stream>>>(wsf, b, out);
    } else {
        hipMemsetAsync(out, 0, (size_t)out_size * sizeof(float), stream);
        power_layer<false><<<grid, dim3(256), 0, stream>>>(x, w, p, b, out);
    }
}

// Round 11
// 105.687 us; speedup vs baseline: 1.2629x; 1.2629x over previous
//
#include <hip/hip_runtime.h>
#include <math.h>

#define EPS 1e-9f

constexpr int Bn = 1024, Dn = 512, Un = 512;
constexpr int BM = 32;      // rows of B per block
constexpr int BU = 64;      // cols of U per block
constexpr int DK = 16;      // k-chunk staged in LDS (14KB/block)

typedef float v4f __attribute__((ext_vector_type(4)));

// XOR swizzle for sL columns (R6-proven: conflicts -> 0).
__device__ __forceinline__ int swz(int d) { return ((d >> 2) & 3) << 3; }

template <int SPLITD, bool USE_WS>
__global__ __launch_bounds__(256, 4) void power_layer(
    const float* __restrict__ x, const float* __restrict__ w,
    const float* __restrict__ p, const float* __restrict__ bias,
    float* __restrict__ outp)
{
    constexpr int DPB    = Dn / SPLITD;
    constexpr int NCHUNK = DPB / DK;

    __shared__ float sL[DK][BM];   // Lenc = sign(neg)*(log2|x+eps|+64), swizzled cols
    __shared__ float sP[DK][BU];   // p
    __shared__ float sW[DK][BU];   // w
    __shared__ float sWX[DK][BU];  // odd(p) ? -w : w

    const int tid = threadIdx.x;
    const int tx  = tid & 15;
    const int ty  = tid >> 4;
    const int tx4 = tx * 4;
    const int ty2 = ty * 2;
    const int ub = blockIdx.x * BU;
    const int bb = blockIdx.y * BM;
    const int d0 = blockIdx.z * DPB;

    v4f acc[2] = {};   // 2 rows x 4 cols per thread

    for (int ch = 0; ch < NCHUNK; ++ch) {
        const int db = d0 + ch * DK;

        // ---- stage x tile -> sL (32 rows x 16 d, transposed+swizzled) ----
        if (tid < 128) {
            const int r  = tid >> 2;          // 0..31
            const int dq = (tid & 3) << 2;    // 0,4,8,12
            const float4 xv = *reinterpret_cast<const float4*>(
                &x[(size_t)(bb + r) * Dn + db + dq]);
            const float* xs = reinterpret_cast<const float*>(&xv);
            #pragma unroll
            for (int j = 0; j < 4; ++j) {
                const float xe = xs[j] + EPS;
                const float La = __builtin_amdgcn_logf(fabsf(xe)) + 64.0f;
                const int dd = dq + j;
                sL[dd][r ^ swz(dd)] = (xe < 0.0f) ? -La : La;
            }
        }
        // ---- stage p,w tiles (16 d x 64 u, natural layout, 1 float4/thread) ----
        {
            const int d  = tid >> 4;          // 0..15
            const int uq = (tid & 15) << 2;   // 0..60
            const size_t gi = (size_t)(db + d) * Un + ub + uq;
            const float4 pv = *reinterpret_cast<const float4*>(&p[gi]);
            const float4 wv = *reinterpret_cast<const float4*>(&w[gi]);
            const float* ps  = reinterpret_cast<const float*>(&pv);
            const float* wsv = reinterpret_cast<const float*>(&wv);
            float4 wxv;
            float* wxs = reinterpret_cast<float*>(&wxv);
            #pragma unroll
            for (int j = 0; j < 4; ++j) {
                const bool odd = (fmodf(ps[j], 2.0f) != 0.0f);
                wxs[j] = odd ? -wsv[j] : wsv[j];
            }
            *reinterpret_cast<float4*>(&sP[d][uq])  = pv;
            *reinterpret_cast<float4*>(&sW[d][uq])  = wv;
            *reinterpret_cast<float4*>(&sWX[d][uq]) = wxv;
        }
        __syncthreads();

        // ---- inner loop: per d, per-row ADDRESS-selected weight fragment ----
        #pragma unroll 4
        for (int d = 0; d < DK; ++d) {
            const float2 Lv = *reinterpret_cast<const float2*>(&sL[d][ty2 ^ swz(d)]);
            const v4f    Pv = *reinterpret_cast<const v4f*>(&sP[d][tx4]);
            const float* Ls = reinterpret_cast<const float*>(&Lv);

            #pragma unroll
            for (int r = 0; r < 2; ++r) {
                const float Ld = fabsf(Ls[r]) - 64.0f;
                const bool  ng = Ls[r] < 0.0f;
                const v4f Wsel = *reinterpret_cast<const v4f*>(
                    ng ? &sWX[d][tx4] : &sW[d][tx4]);

                const v4f t = Pv * Ld;            // v_pk_mul_f32 x2
                v4f e;
                #pragma unroll
                for (int c = 0; c < 4; ++c)
                    e[c] = __builtin_amdgcn_exp2f(t[c]);
                acc[r] = __builtin_elementwise_fma(Wsel, e, acc[r]);  // v_pk_fma_f32 x2
            }
        }
        __syncthreads();
    }

    if (USE_WS) {
        // plain coalesced partial stores: ws[z][b][u]
        float* dst = outp + ((size_t)blockIdx.z * Bn + bb + ty2) * Un + ub + tx4;
        #pragma unroll
        for (int r = 0; r < 2; ++r)
            *reinterpret_cast<v4f*>(dst + (size_t)r * Un) = acc[r];
    } else {
        if (blockIdx.z == 0) {
            const v4f bv = *reinterpret_cast<const v4f*>(&bias[ub + tx4]);
            #pragma unroll
            for (int r = 0; r < 2; ++r)
                acc[r] += bv;
        }
        #pragma unroll
        for (int r = 0; r < 2; ++r) {
            const int row = bb + ty2 + r;
            #pragma unroll
            for (int c = 0; c < 4; ++c)
                atomicAdd(&outp[(size_t)row * Un + ub + tx4 + c], acc[r][c]);
        }
    }
}

// out[b,u] = sum_z ws[z][b][u] + bias[u]   (float4 per thread)
template <int SPLITD>
__global__ __launch_bounds__(256) void reduce_ws(
    const float* __restrict__ ws, const float* __restrict__ bias,
    float* __restrict__ out)
{
    const int nf4 = (Bn * Un) / 4;   // 131072
    const int i = blockIdx.x * 256 + threadIdx.x;
    if (i >= nf4) return;
    const v4f* w4 = reinterpret_cast<const v4f*>(ws);
    v4f a = w4[i];
    #pragma unroll
    for (int z = 1; z < SPLITD; ++z)
        a += w4[(size_t)z * nf4 + i];
    a += reinterpret_cast<const v4f*>(bias)[i & (Un / 4 - 1)];
    reinterpret_cast<v4f*>(out)[i] = a;
}

extern "C" void kernel_launch(void* const* d_in, const int* in_sizes, int n_in,
                              void* d_out, int out_size, void* d_ws, size_t ws_size,
                              hipStream_t stream) {
    const float* x = (const float*)d_in[0];
    const float* w = (const float*)d_in[1];
    const float* p = (const float*)d_in[2];
    const float* b = (const float*)d_in[3];
    float* out = (float*)d_out;

    const size_t need16 = (size_t)16 * Bn * Un * sizeof(float);   // 32 MB
    const size_t need8  = (size_t)8  * Bn * Un * sizeof(float);   // 16 MB
    const dim3 blk(256);
    const dim3 rgrid((Bn * Un / 4 + 255) / 256);

    if (ws_size >= need16) {
        // 4096 blocks = 16/CU dispatched, ~8 resident: staggered rounds
        float* wsf = (float*)d_ws;
        power_layer<16, true><<<dim3(Un / BU, Bn / BM, 16), blk, 0, stream>>>(x, w, p, b, wsf);
        reduce_ws<16><<<rgrid, blk, 0, stream>>>(wsf, b, out);
    } else if (ws_size >= need8) {
        // proven R7 path
        float* wsf = (float*)d_ws;
        power_layer<8, true><<<dim3(Un / BU, Bn / BM, 8), blk, 0, stream>>>(x, w, p, b, wsf);
        reduce_ws<8><<<rgrid, blk, 0, stream>>>(wsf, b, out);
    } else {
        hipMemsetAsync(out, 0, (size_t)out_size * sizeof(float), stream);
        power_layer<8, false><<<dim3(Un / BU, Bn / BM, 8), blk, 0, stream>>>(x, w, p, b, out);
    }
}

// Round 12
// 104.872 us; speedup vs baseline: 1.2727x; 1.0078x over previous
//
#include <hip/hip_runtime.h>
#include <math.h>

#define EPS 1e-9f

constexpr int Bn = 1024, Dn = 512, Un = 512;
constexpr int BM = 64;      // rows of B per block (4x4 per thread)
constexpr int BU = 64;      // cols of U per block
constexpr int DK = 16;      // k-chunk staged in LDS (16KB/block)

typedef float v4f __attribute__((ext_vector_type(4)));

// XOR swizzle for sL columns (R6-proven: conflicts -> 0). Multiples of 8,
// preserves b128 alignment of 4-float groups.
__device__ __forceinline__ int swz(int d) { return ((d >> 2) & 3) << 3; }

template <int SPLITD, bool USE_WS>
__global__ __launch_bounds__(256, 4) void power_layer(
    const float* __restrict__ x, const float* __restrict__ w,
    const float* __restrict__ p, const float* __restrict__ bias,
    float* __restrict__ outp)
{
    constexpr int DPB    = Dn / SPLITD;
    constexpr int NCHUNK = DPB / DK;

    __shared__ float sL[DK][BM];   // Lenc = sign(neg)*(log2|x+eps|+64), swizzled cols
    __shared__ float sP[DK][BU];   // p
    __shared__ float sW[DK][BU];   // w
    __shared__ float sWX[DK][BU];  // odd(p) ? -w : w

    const int tid = threadIdx.x;
    const int tx  = tid & 15;
    const int ty  = tid >> 4;
    const int tx4 = tx * 4;
    const int ty4 = ty * 4;
    const int ub = blockIdx.x * BU;
    const int bb = blockIdx.y * BM;
    const int d0 = blockIdx.z * DPB;

    v4f acc[4] = {};   // 4 rows x 4 cols per thread

    for (int ch = 0; ch < NCHUNK; ++ch) {
        const int db = d0 + ch * DK;

        // ---- stage x tile -> sL (64 rows x 16 d, transposed+swizzled) ----
        // 256 float4 loads, 1 per thread.
        {
            const int r  = tid >> 2;          // 0..63
            const int dq = (tid & 3) << 2;    // 0,4,8,12
            const float4 xv = *reinterpret_cast<const float4*>(
                &x[(size_t)(bb + r) * Dn + db + dq]);
            const float* xs = reinterpret_cast<const float*>(&xv);
            #pragma unroll
            for (int j = 0; j < 4; ++j) {
                const float xe = xs[j] + EPS;
                const float La = __builtin_amdgcn_logf(fabsf(xe)) + 64.0f;
                const int dd = dq + j;
                sL[dd][r ^ swz(dd)] = (xe < 0.0f) ? -La : La;
            }
        }
        // ---- stage p,w tiles (16 d x 64 u, natural layout, 1 float4/thread) ----
        {
            const int d  = tid >> 4;          // 0..15
            const int uq = (tid & 15) << 2;   // 0..60
            const size_t gi = (size_t)(db + d) * Un + ub + uq;
            const float4 pv = *reinterpret_cast<const float4*>(&p[gi]);
            const float4 wv = *reinterpret_cast<const float4*>(&w[gi]);
            const float* ps  = reinterpret_cast<const float*>(&pv);
            const float* wsv = reinterpret_cast<const float*>(&wv);
            float4 wxv;
            float* wxs = reinterpret_cast<float*>(&wxv);
            #pragma unroll
            for (int j = 0; j < 4; ++j) {
                const bool odd = (fmodf(ps[j], 2.0f) != 0.0f);
                wxs[j] = odd ? -wsv[j] : wsv[j];
            }
            *reinterpret_cast<float4*>(&sP[d][uq])  = pv;
            *reinterpret_cast<float4*>(&sW[d][uq])  = wv;
            *reinterpret_cast<float4*>(&sWX[d][uq]) = wxv;
        }
        __syncthreads();

        // ---- inner loop: 4 b128 reads per d feed 16 elements/thread ----
        // (halves LDS-pipe cycles/element vs the 2x4 tile: the inner-loop
        //  LDS pipe was co-saturated with VALU at ~37.5us each)
        #pragma unroll 2
        for (int d = 0; d < DK; ++d) {
            const v4f Lv = *reinterpret_cast<const v4f*>(&sL[d][ty4 ^ swz(d)]);
            const v4f Pv = *reinterpret_cast<const v4f*>(&sP[d][tx4]);
            const v4f Wv = *reinterpret_cast<const v4f*>(&sW[d][tx4]);
            const v4f Xv = *reinterpret_cast<const v4f*>(&sWX[d][tx4]);

            float Ld[4];
            bool  ng[4];
            #pragma unroll
            for (int r = 0; r < 4; ++r) {
                Ld[r] = fabsf(Lv[r]) - 64.0f;
                ng[r] = Lv[r] < 0.0f;
            }

            // batch all 16 independent exps before any consumer
            v4f e[4];
            #pragma unroll
            for (int r = 0; r < 4; ++r) {
                const v4f t = Pv * Ld[r];         // v_pk_mul_f32 x2
                #pragma unroll
                for (int c = 0; c < 4; ++c)
                    e[r][c] = __builtin_amdgcn_exp2f(t[c]);
            }

            #pragma unroll
            for (int r = 0; r < 4; ++r) {
                v4f wsel;
                #pragma unroll
                for (int c = 0; c < 4; ++c)
                    wsel[c] = ng[r] ? Xv[c] : Wv[c];   // v_cndmask
                acc[r] = __builtin_elementwise_fma(wsel, e[r], acc[r]);  // v_pk_fma x2
            }
        }
        __syncthreads();
    }

    if (USE_WS) {
        // plain coalesced partial stores: ws[z][b][u]
        float* dst = outp + ((size_t)blockIdx.z * Bn + bb + ty4) * Un + ub + tx4;
        #pragma unroll
        for (int r = 0; r < 4; ++r)
            *reinterpret_cast<v4f*>(dst + (size_t)r * Un) = acc[r];
    } else {
        if (blockIdx.z == 0) {
            const v4f bv = *reinterpret_cast<const v4f*>(&bias[ub + tx4]);
            #pragma unroll
            for (int r = 0; r < 4; ++r)
                acc[r] += bv;
        }
        #pragma unroll
        for (int r = 0; r < 4; ++r) {
            const int row = bb + ty4 + r;
            #pragma unroll
            for (int c = 0; c < 4; ++c)
                atomicAdd(&outp[(size_t)row * Un + ub + tx4 + c], acc[r][c]);
        }
    }
}

// out[b,u] = sum_z ws[z][b][u] + bias[u]   (float4 per thread)
template <int SPLITD>
__global__ __launch_bounds__(256) void reduce_ws(
    const float* __restrict__ ws, const float* __restrict__ bias,
    float* __restrict__ out)
{
    const int nf4 = (Bn * Un) / 4;   // 131072
    const int i = blockIdx.x * 256 + threadIdx.x;
    if (i >= nf4) return;
    const v4f* w4 = reinterpret_cast<const v4f*>(ws);
    v4f a = w4[i];
    #pragma unroll
    for (int z = 1; z < SPLITD; ++z)
        a += w4[(size_t)z * nf4 + i];
    a += reinterpret_cast<const v4f*>(bias)[i & (Un / 4 - 1)];
    reinterpret_cast<v4f*>(out)[i] = a;
}

extern "C" void kernel_launch(void* const* d_in, const int* in_sizes, int n_in,
                              void* d_out, int out_size, void* d_ws, size_t ws_size,
                              hipStream_t stream) {
    const float* x = (const float*)d_in[0];
    const float* w = (const float*)d_in[1];
    const float* p = (const float*)d_in[2];
    const float* b = (const float*)d_in[3];
    float* out = (float*)d_out;

    const size_t need16 = (size_t)16 * Bn * Un * sizeof(float);   // 32 MB
    const size_t need8  = (size_t)8  * Bn * Un * sizeof(float);   // 16 MB
    const dim3 blk(256);
    const dim3 rgrid((Bn * Un / 4 + 255) / 256);

    if (ws_size >= need16) {
        // 8 x 16 x 16 = 2048 blocks
        float* wsf = (float*)d_ws;
        power_layer<16, true><<<dim3(Un / BU, Bn / BM, 16), blk, 0, stream>>>(x, w, p, b, wsf);
        reduce_ws<16><<<rgrid, blk, 0, stream>>>(wsf, b, out);
    } else if (ws_size >= need8) {
        float* wsf = (float*)d_ws;
        power_layer<8, true><<<dim3(Un / BU, Bn / BM, 8), blk, 0, stream>>>(x, w, p, b, wsf);
        reduce_ws<8><<<rgrid, blk, 0, stream>>>(wsf, b, out);
    } else {
        hipMemsetAsync(out, 0, (size_t)out_size * sizeof(float), stream);
        power_layer<8, false><<<dim3(Un / BU, Bn / BM, 8), blk, 0, stream>>>(x, w, p, b, out);
    }
}